// Round 1
// baseline (1260.943 us; speedup 1.0000x reference)
//
#include <hip/hip_runtime.h>
#include <hip/hip_bf16.h>

// Problem constants
#define T_TOK 8192      // BATCH*SEQ
#define DM    1024      // D_MODEL
#define NE    8         // NUM_EXPERTS
#define HID   2048      // HIDDEN == SHARED_HIDDEN
#define REXP  16384     // 2*T (expert pair rows)
#define RTOT  24576     // 2*T + T (expert pairs + shared rows)

typedef __attribute__((ext_vector_type(8))) short bf16x8;
typedef __attribute__((ext_vector_type(4))) float f32x4;

__device__ __forceinline__ unsigned short f2bf(float f) {
  // round-to-nearest-even fp32 -> bf16 (inputs finite)
  unsigned int u = __float_as_uint(f);
  unsigned int r = (u + 0x7FFFu + ((u >> 16) & 1u)) >> 16;
  return (unsigned short)r;
}

// ---------------- cast x (fp32 -> bf16), 4 elems/thread ----------------
__global__ void cast_x_k(const float* __restrict__ x, unsigned short* __restrict__ xb) {
  int i = blockIdx.x * 256 + threadIdx.x;
  float4 v = ((const float4*)x)[i];
  ushort4 o;
  o.x = f2bf(v.x); o.y = f2bf(v.y); o.z = f2bf(v.z); o.w = f2bf(v.w);
  ((ushort4*)xb)[i] = o;
}

// ------------- transpose + cast: src [R,C] fp32 -> dst [C,R] bf16 -------------
__global__ void transpose_cast_k(const float* __restrict__ src, unsigned short* __restrict__ dst,
                                 int R, int C) {
  __shared__ float tile[32][33];
  const float* s = src + (size_t)blockIdx.z * R * C;
  unsigned short* d = dst + (size_t)blockIdx.z * R * C;
  int c0 = blockIdx.x * 32, r0 = blockIdx.y * 32;
  int tx = threadIdx.x, ty = threadIdx.y; // 32 x 8
#pragma unroll
  for (int i = 0; i < 32; i += 8)
    tile[ty + i][tx] = s[(size_t)(r0 + ty + i) * C + c0 + tx];
  __syncthreads();
#pragma unroll
  for (int i = 0; i < 32; i += 8)
    d[(size_t)(c0 + ty + i) * R + r0 + tx] = f2bf(tile[tx][ty + i]);
}

// ---------------- router: fp32 logits -> softmax -> top2 ----------------
// meta layout (ints): [0..7]=counts  [8..23]=roff  [24..31]=cursor  [32..47]=rcount
__global__ void router_k(const float* __restrict__ x, const float* __restrict__ wr,
                         int* __restrict__ meta, int* __restrict__ te, float* __restrict__ tw) {
  int t = blockIdx.x * 256 + threadIdx.x;
  const float* xr = x + (size_t)t * DM;
  float acc[NE] = {};
  for (int d = 0; d < DM; d += 4) {
    float4 v = *(const float4*)(xr + d);
#pragma unroll
    for (int e = 0; e < NE; ++e) {
      acc[e] += v.x * wr[(d + 0) * NE + e] + v.y * wr[(d + 1) * NE + e]
              + v.z * wr[(d + 2) * NE + e] + v.w * wr[(d + 3) * NE + e];
    }
  }
  float m = acc[0];
#pragma unroll
  for (int e = 1; e < NE; ++e) m = fmaxf(m, acc[e]);
  float p[NE]; float s = 0.f;
#pragma unroll
  for (int e = 0; e < NE; ++e) { p[e] = __expf(acc[e] - m); s += p[e]; }
  float inv = 1.f / s;
  int i0 = 0;
#pragma unroll
  for (int e = 1; e < NE; ++e) if (p[e] > p[i0]) i0 = e;
  int i1 = (i0 == 0) ? 1 : 0;
#pragma unroll
  for (int e = 0; e < NE; ++e) if (e != i0 && p[e] > p[i1]) i1 = e;
  atomicAdd(&meta[i0], 1);
  atomicAdd(&meta[i1], 1);
  te[t * 2 + 0] = i0; te[t * 2 + 1] = i1;
  tw[t * 2 + 0] = p[i0] * inv; tw[t * 2 + 1] = p[i1] * inv;
}

// ---------------- tiny scan: counts -> row offsets ----------------
__global__ void scan_k(int* __restrict__ meta) {
  if (threadIdx.x == 0) {
    int* counts = meta; int* roff = meta + 8; int* cursor = meta + 24; int* rcount = meta + 32;
    int acc = 0;
    for (int e = 0; e < NE; ++e) { roff[e] = acc; cursor[e] = acc; rcount[e] = counts[e]; acc += counts[e]; }
    roff[NE] = REXP;      // shared "expert" rows live at [REXP, RTOT)
    rcount[NE] = T_TOK;
  }
}

// ---------------- build compacted pair lists ----------------
__global__ void build_k(const int* __restrict__ te, const float* __restrict__ tw,
                        int* __restrict__ meta, int* __restrict__ tok_list, float* __restrict__ srow) {
  int t = blockIdx.x * 256 + threadIdx.x;
  int* cursor = meta + 24;
#pragma unroll
  for (int k = 0; k < 2; ++k) {
    int e = te[t * 2 + k];
    int pos = atomicAdd(&cursor[e], 1);
    tok_list[pos] = t;
    srow[pos] = tw[t * 2 + k] * (2.0f / 3.0f);   // moe_out * K/(K+1)
  }
  tok_list[REXP + t] = t;
  srow[REXP + t] = 1.0f / 3.0f;                  // shared / (K+1)
}

// ---------------- GEMM1: Hg = silu(Xg @ W1) * (Xg @ W3), gathered rows ----------------
// A: xb [T,DM] bf16 gathered via tok_list; B: wt [n=HID][k=DM] bf16 (transposed); out Hg [RTOT,HID] bf16
__global__ __launch_bounds__(256) void gemm1_k(
    const unsigned short* __restrict__ xb,
    const unsigned short* __restrict__ wt1, const unsigned short* __restrict__ wt3,
    const unsigned short* __restrict__ wst1, const unsigned short* __restrict__ wst3,
    unsigned short* __restrict__ Hg,
    const int* __restrict__ tok_list, const int* __restrict__ meta) {
  const int* roff = meta + 8; const int* rcount = meta + 32;
  int e = blockIdx.z;
  int cnt = rcount[e];
  int m0 = blockIdx.y * 128;
  if (m0 >= cnt) return;
  int rbase = roff[e];
  int n0 = blockIdx.x * 128;

  __shared__ int tok_s[128];
  __shared__ __align__(16) unsigned short la[128 * 32];
  __shared__ __align__(16) unsigned short lb1[128 * 32];
  __shared__ __align__(16) unsigned short lb3[128 * 32];

  int tid = threadIdx.x;
  if (tid < 128) {
    int r = m0 + tid;
    tok_s[tid] = (r < cnt) ? tok_list[rbase + r] : -1;
  }
  __syncthreads();

  const unsigned short* b1 = (e < NE) ? (wt1 + (size_t)e * HID * DM) : wst1;
  const unsigned short* b3 = (e < NE) ? (wt3 + (size_t)e * HID * DM) : wst3;

  int wave = tid >> 6, lane = tid & 63;
  int wm = (wave >> 1) << 6, wn = (wave & 1) << 6;
  int lq = lane >> 4, lr = lane & 15;

  f32x4 acc1[4][4] = {}; f32x4 acc3[4][4] = {};

  for (int k0 = 0; k0 < DM; k0 += 32) {
#pragma unroll
    for (int it = 0; it < 2; ++it) {
      int seg = it * 256 + tid;
      int row = seg >> 2;
      int q = (seg & 3) << 3;
      int tok = tok_s[row];
      uint4 va = make_uint4(0, 0, 0, 0);
      if (tok >= 0) va = *(const uint4*)(xb + (size_t)tok * DM + k0 + q);
      *(uint4*)(&la[row * 32 + q]) = va;
      *(uint4*)(&lb1[row * 32 + q]) = *(const uint4*)(b1 + (size_t)(n0 + row) * DM + k0 + q);
      *(uint4*)(&lb3[row * 32 + q]) = *(const uint4*)(b3 + (size_t)(n0 + row) * DM + k0 + q);
    }
    __syncthreads();
    bf16x8 af[4], bf1[4], bf3[4];
#pragma unroll
    for (int i = 0; i < 4; ++i) {
      af[i]  = *(const bf16x8*)(&la[(wm + i * 16 + lr) * 32 + lq * 8]);
      bf1[i] = *(const bf16x8*)(&lb1[(wn + i * 16 + lr) * 32 + lq * 8]);
      bf3[i] = *(const bf16x8*)(&lb3[(wn + i * 16 + lr) * 32 + lq * 8]);
    }
#pragma unroll
    for (int i = 0; i < 4; ++i)
#pragma unroll
      for (int j = 0; j < 4; ++j) {
        acc1[i][j] = __builtin_amdgcn_mfma_f32_16x16x32_bf16(af[i], bf1[j], acc1[i][j], 0, 0, 0);
        acc3[i][j] = __builtin_amdgcn_mfma_f32_16x16x32_bf16(af[i], bf3[j], acc3[i][j], 0, 0, 0);
      }
    __syncthreads();
  }

#pragma unroll
  for (int i = 0; i < 4; ++i)
#pragma unroll
    for (int j = 0; j < 4; ++j)
#pragma unroll
      for (int r = 0; r < 4; ++r) {
        int lm = wm + i * 16 + lq * 4 + r;          // C/D: row = quad*4 + reg
        if (m0 + lm < cnt) {
          int ln = wn + j * 16 + lr;                // C/D: col = lane&15
          float a = acc1[i][j][r];
          float c = acc3[i][j][r];
          float h = (a / (1.f + __expf(-a))) * c;   // silu(a) * c
          Hg[(size_t)(rbase + m0 + lm) * HID + n0 + ln] = f2bf(h);
        }
      }
}

// ---------------- GEMM2: out[tok] += scale * (Hg_row @ W2) ----------------
// A: Hg [RTOT,HID]; B: wt2 [n=DM][k=HID] (transposed); scatter atomicAdd into out [T,DM] fp32
__global__ __launch_bounds__(256) void gemm2_k(
    const unsigned short* __restrict__ Hg,
    const unsigned short* __restrict__ wt2, const unsigned short* __restrict__ wst2,
    float* __restrict__ out,
    const int* __restrict__ tok_list, const float* __restrict__ srow,
    const int* __restrict__ meta) {
  const int* roff = meta + 8; const int* rcount = meta + 32;
  int e = blockIdx.z;
  int cnt = rcount[e];
  int m0 = blockIdx.y * 128;
  if (m0 >= cnt) return;
  int rbase = roff[e];
  int n0 = blockIdx.x * 128;

  __shared__ int tok_s[128];
  __shared__ float sc_s[128];
  __shared__ __align__(16) unsigned short la[128 * 32];
  __shared__ __align__(16) unsigned short lb[128 * 32];

  int tid = threadIdx.x;
  if (tid < 128) {
    int r = m0 + tid;
    tok_s[tid] = (r < cnt) ? tok_list[rbase + r] : -1;
    sc_s[tid] = (r < cnt) ? srow[rbase + r] : 0.f;
  }
  __syncthreads();

  const unsigned short* b = (e < NE) ? (wt2 + (size_t)e * DM * HID) : wst2;

  int wave = tid >> 6, lane = tid & 63;
  int wm = (wave >> 1) << 6, wn = (wave & 1) << 6;
  int lq = lane >> 4, lr = lane & 15;

  f32x4 acc[4][4] = {};

  for (int k0 = 0; k0 < HID; k0 += 32) {
#pragma unroll
    for (int it = 0; it < 2; ++it) {
      int seg = it * 256 + tid;
      int row = seg >> 2;
      int q = (seg & 3) << 3;
      // padding rows (beyond cnt) read adjacent-region bf16 garbage; their C rows are never stored
      *(uint4*)(&la[row * 32 + q]) = *(const uint4*)(Hg + (size_t)(rbase + m0 + row) * HID + k0 + q);
      *(uint4*)(&lb[row * 32 + q]) = *(const uint4*)(b + (size_t)(n0 + row) * HID + k0 + q);
    }
    __syncthreads();
    bf16x8 af[4], bfv[4];
#pragma unroll
    for (int i = 0; i < 4; ++i) {
      af[i]  = *(const bf16x8*)(&la[(wm + i * 16 + lr) * 32 + lq * 8]);
      bfv[i] = *(const bf16x8*)(&lb[(wn + i * 16 + lr) * 32 + lq * 8]);
    }
#pragma unroll
    for (int i = 0; i < 4; ++i)
#pragma unroll
      for (int j = 0; j < 4; ++j)
        acc[i][j] = __builtin_amdgcn_mfma_f32_16x16x32_bf16(af[i], bfv[j], acc[i][j], 0, 0, 0);
    __syncthreads();
  }

#pragma unroll
  for (int i = 0; i < 4; ++i)
#pragma unroll
    for (int j = 0; j < 4; ++j)
#pragma unroll
      for (int r = 0; r < 4; ++r) {
        int lm = wm + i * 16 + lq * 4 + r;
        if (m0 + lm < cnt) {
          int tok = tok_s[lm];
          int ln = wn + j * 16 + lr;
          float v = acc[i][j][r] * sc_s[lm];
          unsafeAtomicAdd(&out[(size_t)tok * DM + n0 + ln], v);
        }
      }
}

// ---------------- launch ----------------
extern "C" void kernel_launch(void* const* d_in, const int* in_sizes, int n_in,
                              void* d_out, int out_size, void* d_ws, size_t ws_size,
                              hipStream_t stream) {
  const float* x   = (const float*)d_in[0];
  const float* wr  = (const float*)d_in[1];
  const float* w1  = (const float*)d_in[2];
  const float* w3  = (const float*)d_in[3];
  const float* w2  = (const float*)d_in[4];
  const float* ws1 = (const float*)d_in[5];
  const float* ws3 = (const float*)d_in[6];
  const float* ws2 = (const float*)d_in[7];
  float* out = (float*)d_out;

  // workspace carve-up (~231 MB total)
  char* p = (char*)d_ws;
  auto alloc = [&](size_t bytes) { char* r = p; p += (bytes + 255) & ~(size_t)255; return r; };
  unsigned short* xb   = (unsigned short*)alloc((size_t)T_TOK * DM * 2);
  unsigned short* wt1  = (unsigned short*)alloc((size_t)NE * HID * DM * 2);
  unsigned short* wt3  = (unsigned short*)alloc((size_t)NE * HID * DM * 2);
  unsigned short* wt2  = (unsigned short*)alloc((size_t)NE * DM * HID * 2);
  unsigned short* wst1 = (unsigned short*)alloc((size_t)HID * DM * 2);
  unsigned short* wst3 = (unsigned short*)alloc((size_t)HID * DM * 2);
  unsigned short* wst2 = (unsigned short*)alloc((size_t)DM * HID * 2);
  unsigned short* Hg   = (unsigned short*)alloc((size_t)RTOT * HID * 2);
  int*   tok_list = (int*)alloc((size_t)RTOT * 4);
  float* srow     = (float*)alloc((size_t)RTOT * 4);
  int*   te       = (int*)alloc((size_t)T_TOK * 2 * 4);
  float* tw       = (float*)alloc((size_t)T_TOK * 2 * 4);
  int*   meta     = (int*)alloc(256);
  (void)ws_size; (void)in_sizes; (void)n_in;

  hipMemsetAsync(meta, 0, 256, stream);
  hipMemsetAsync(out, 0, (size_t)out_size * sizeof(float), stream);

  cast_x_k<<<(T_TOK * DM / 4) / 256, 256, 0, stream>>>(x, xb);

  dim3 tb(32, 8);
  transpose_cast_k<<<dim3(HID / 32, DM / 32, NE), tb, 0, stream>>>(w1, wt1, DM, HID);
  transpose_cast_k<<<dim3(HID / 32, DM / 32, NE), tb, 0, stream>>>(w3, wt3, DM, HID);
  transpose_cast_k<<<dim3(DM / 32, HID / 32, NE), tb, 0, stream>>>(w2, wt2, HID, DM);
  transpose_cast_k<<<dim3(HID / 32, DM / 32, 1), tb, 0, stream>>>(ws1, wst1, DM, HID);
  transpose_cast_k<<<dim3(HID / 32, DM / 32, 1), tb, 0, stream>>>(ws3, wst3, DM, HID);
  transpose_cast_k<<<dim3(DM / 32, HID / 32, 1), tb, 0, stream>>>(ws2, wst2, HID, DM);

  router_k<<<T_TOK / 256, 256, 0, stream>>>(x, wr, meta, te, tw);
  scan_k<<<1, 64, 0, stream>>>(meta);
  build_k<<<T_TOK / 256, 256, 0, stream>>>(te, tw, meta, tok_list, srow);

  gemm1_k<<<dim3(HID / 128, 64, NE + 1), 256, 0, stream>>>(xb, wt1, wt3, wst1, wst3, Hg, tok_list, meta);
  gemm2_k<<<dim3(DM / 128, 64, NE + 1), 256, 0, stream>>>(Hg, wt2, wst2, out, tok_list, srow, meta);
}

// Round 2
// 1230.917 us; speedup vs baseline: 1.0244x; 1.0244x over previous
//
#include <hip/hip_runtime.h>
#include <hip/hip_bf16.h>

// Problem constants
#define T_TOK 8192      // BATCH*SEQ
#define DM    1024      // D_MODEL
#define NE    8         // NUM_EXPERTS
#define HID   2048      // HIDDEN == SHARED_HIDDEN
#define REXP  16384     // 2*T (expert pair rows)
#define RTOT  24576     // 2*T + T (expert pairs + shared rows)

typedef __attribute__((ext_vector_type(8))) short bf16x8;
typedef __attribute__((ext_vector_type(4))) float f32x4;

__device__ __forceinline__ unsigned short f2bf(float f) {
  unsigned int u = __float_as_uint(f);
  unsigned int r = (u + 0x7FFFu + ((u >> 16) & 1u)) >> 16;
  return (unsigned short)r;
}

// async global -> LDS, 16 bytes per lane. LDS dst must be wave-uniform base +
// lane*16 contiguous (it is: chunk index = it*256+tid).
__device__ __forceinline__ void gl2l(const unsigned short* g, unsigned short* l) {
  const unsigned int* g32 = (const unsigned int*)g;
  unsigned int* l32 = (unsigned int*)l;
  __builtin_amdgcn_global_load_lds(
      (const __attribute__((address_space(1))) unsigned int*)g32,
      (__attribute__((address_space(3))) unsigned int*)l32, 16, 0, 0);
}

// ---------------- cast x (fp32 -> bf16), 4 elems/thread ----------------
__global__ void cast_x_k(const float* __restrict__ x, unsigned short* __restrict__ xb) {
  int i = blockIdx.x * 256 + threadIdx.x;
  float4 v = ((const float4*)x)[i];
  ushort4 o;
  o.x = f2bf(v.x); o.y = f2bf(v.y); o.z = f2bf(v.z); o.w = f2bf(v.w);
  ((ushort4*)xb)[i] = o;
}

// ------------- transpose + cast: src [R,C] fp32 -> dst [C,R] bf16 -------------
__global__ void transpose_cast_k(const float* __restrict__ src, unsigned short* __restrict__ dst,
                                 int R, int C) {
  __shared__ float tile[32][33];
  const float* s = src + (size_t)blockIdx.z * R * C;
  unsigned short* d = dst + (size_t)blockIdx.z * R * C;
  int c0 = blockIdx.x * 32, r0 = blockIdx.y * 32;
  int tx = threadIdx.x, ty = threadIdx.y; // 32 x 8
#pragma unroll
  for (int i = 0; i < 32; i += 8)
    tile[ty + i][tx] = s[(size_t)(r0 + ty + i) * C + c0 + tx];
  __syncthreads();
#pragma unroll
  for (int i = 0; i < 32; i += 8)
    d[(size_t)(c0 + ty + i) * R + r0 + tx] = f2bf(tile[tx][ty + i]);
}

// ---------------- router: fp32 logits -> softmax -> top2 ----------------
// meta layout (ints): [0..7]=counts  [8..23]=roff  [24..31]=cursor  [32..47]=rcount
__global__ void router_k(const float* __restrict__ x, const float* __restrict__ wr,
                         int* __restrict__ meta, int* __restrict__ te, float* __restrict__ tw) {
  int t = blockIdx.x * 256 + threadIdx.x;
  const float* xr = x + (size_t)t * DM;
  float acc[NE] = {};
  for (int d = 0; d < DM; d += 4) {
    float4 v = *(const float4*)(xr + d);
#pragma unroll
    for (int e = 0; e < NE; ++e) {
      acc[e] += v.x * wr[(d + 0) * NE + e] + v.y * wr[(d + 1) * NE + e]
              + v.z * wr[(d + 2) * NE + e] + v.w * wr[(d + 3) * NE + e];
    }
  }
  float m = acc[0];
#pragma unroll
  for (int e = 1; e < NE; ++e) m = fmaxf(m, acc[e]);
  float p[NE]; float s = 0.f;
#pragma unroll
  for (int e = 0; e < NE; ++e) { p[e] = __expf(acc[e] - m); s += p[e]; }
  float inv = 1.f / s;
  int i0 = 0;
#pragma unroll
  for (int e = 1; e < NE; ++e) if (p[e] > p[i0]) i0 = e;
  int i1 = (i0 == 0) ? 1 : 0;
#pragma unroll
  for (int e = 0; e < NE; ++e) if (e != i0 && p[e] > p[i1]) i1 = e;
  atomicAdd(&meta[i0], 1);
  atomicAdd(&meta[i1], 1);
  te[t * 2 + 0] = i0; te[t * 2 + 1] = i1;
  tw[t * 2 + 0] = p[i0] * inv; tw[t * 2 + 1] = p[i1] * inv;
}

// ---------------- tiny scan: counts -> row offsets ----------------
__global__ void scan_k(int* __restrict__ meta) {
  if (threadIdx.x == 0) {
    int* counts = meta; int* roff = meta + 8; int* cursor = meta + 24; int* rcount = meta + 32;
    int acc = 0;
    for (int e = 0; e < NE; ++e) { roff[e] = acc; cursor[e] = acc; rcount[e] = counts[e]; acc += counts[e]; }
    roff[NE] = REXP;      // shared "expert" rows live at [REXP, RTOT)
    rcount[NE] = T_TOK;
  }
}

// ---------------- build compacted pair lists ----------------
__global__ void build_k(const int* __restrict__ te, const float* __restrict__ tw,
                        int* __restrict__ meta, int* __restrict__ tok_list, float* __restrict__ srow) {
  int t = blockIdx.x * 256 + threadIdx.x;
  int* cursor = meta + 24;
#pragma unroll
  for (int k = 0; k < 2; ++k) {
    int e = te[t * 2 + k];
    int pos = atomicAdd(&cursor[e], 1);
    tok_list[pos] = t;
    srow[pos] = tw[t * 2 + k] * (2.0f / 3.0f);   // moe_out * K/(K+1)
  }
  tok_list[REXP + t] = t;
  srow[REXP + t] = 1.0f / 3.0f;                  // shared / (K+1)
}

// ---------------- GEMM1: Hg = silu(Xg @ W1) * (Xg @ W3), gathered rows ----------------
__global__ __launch_bounds__(256) void gemm1_k(
    const unsigned short* __restrict__ xb,
    const unsigned short* __restrict__ wt1, const unsigned short* __restrict__ wt3,
    const unsigned short* __restrict__ wst1, const unsigned short* __restrict__ wst3,
    unsigned short* __restrict__ Hg,
    const int* __restrict__ tok_list, const int* __restrict__ meta) {
  const int* roff = meta + 8; const int* rcount = meta + 32;
  int e = blockIdx.z;
  int cnt = rcount[e];
  int m0 = blockIdx.y * 128;
  if (m0 >= cnt) return;
  int rbase = roff[e];
  int n0 = blockIdx.x * 128;

  __shared__ int tok_s[128];
  __shared__ __align__(16) unsigned short la[128 * 32];
  __shared__ __align__(16) unsigned short lb1[128 * 32];
  __shared__ __align__(16) unsigned short lb3[128 * 32];

  int tid = threadIdx.x;
  if (tid < 128) {
    int r = m0 + tid;
    int tok = (r < cnt) ? tok_list[rbase + r] : 0;  // padding rows -> token 0 (C rows masked at store)
    tok_s[tid] = tok;
  }
  __syncthreads();

  const unsigned short* b1 = (e < NE) ? (wt1 + (size_t)e * HID * DM) : wst1;
  const unsigned short* b3 = (e < NE) ? (wt3 + (size_t)e * HID * DM) : wst3;

  int wave = tid >> 6, lane = tid & 63;
  int wm = (wave >> 1) << 6, wn = (wave & 1) << 6;
  int lq = lane >> 4, lr = lane & 15;

  // per-thread staging coords (2 chunks of 16B per tile per thread)
  int row0 = tid >> 2,             q0 = (tid & 3) << 3;
  int row1 = (256 + tid) >> 2,     q1 = q0;

  f32x4 acc1[4][4] = {}; f32x4 acc3[4][4] = {};

  for (int k0 = 0; k0 < DM; k0 += 32) {
    int t0 = tok_s[row0], t1 = tok_s[row1];
    gl2l(xb + (size_t)t0 * DM + k0 + q0, &la[tid * 8]);
    gl2l(xb + (size_t)t1 * DM + k0 + q1, &la[(256 + tid) * 8]);
    gl2l(b1 + (size_t)(n0 + row0) * DM + k0 + q0, &lb1[tid * 8]);
    gl2l(b1 + (size_t)(n0 + row1) * DM + k0 + q1, &lb1[(256 + tid) * 8]);
    gl2l(b3 + (size_t)(n0 + row0) * DM + k0 + q0, &lb3[tid * 8]);
    gl2l(b3 + (size_t)(n0 + row1) * DM + k0 + q1, &lb3[(256 + tid) * 8]);
    __syncthreads();
    bf16x8 af[4], bf1[4], bf3[4];
#pragma unroll
    for (int i = 0; i < 4; ++i) {
      af[i]  = *(const bf16x8*)(&la[(wm + i * 16 + lr) * 32 + lq * 8]);
      bf1[i] = *(const bf16x8*)(&lb1[(wn + i * 16 + lr) * 32 + lq * 8]);
      bf3[i] = *(const bf16x8*)(&lb3[(wn + i * 16 + lr) * 32 + lq * 8]);
    }
#pragma unroll
    for (int i = 0; i < 4; ++i)
#pragma unroll
      for (int j = 0; j < 4; ++j) {
        acc1[i][j] = __builtin_amdgcn_mfma_f32_16x16x32_bf16(af[i], bf1[j], acc1[i][j], 0, 0, 0);
        acc3[i][j] = __builtin_amdgcn_mfma_f32_16x16x32_bf16(af[i], bf3[j], acc3[i][j], 0, 0, 0);
      }
    __syncthreads();
  }

#pragma unroll
  for (int i = 0; i < 4; ++i)
#pragma unroll
    for (int j = 0; j < 4; ++j)
#pragma unroll
      for (int r = 0; r < 4; ++r) {
        int lm = wm + i * 16 + lq * 4 + r;          // C/D: row = quad*4 + reg
        if (m0 + lm < cnt) {
          int ln = wn + j * 16 + lr;                // C/D: col = lane&15
          float a = acc1[i][j][r];
          float c = acc3[i][j][r];
          float h = (a / (1.f + __expf(-a))) * c;   // silu(a) * c
          Hg[(size_t)(rbase + m0 + lm) * HID + n0 + ln] = f2bf(h);
        }
      }
}

// ---------------- GEMM2: out[tok] += scale * (Hg_row @ W2) ----------------
__global__ __launch_bounds__(256) void gemm2_k(
    const unsigned short* __restrict__ Hg,
    const unsigned short* __restrict__ wt2, const unsigned short* __restrict__ wst2,
    float* __restrict__ out,
    const int* __restrict__ tok_list, const float* __restrict__ srow,
    const int* __restrict__ meta) {
  const int* roff = meta + 8; const int* rcount = meta + 32;
  int e = blockIdx.z;
  int cnt = rcount[e];
  int m0 = blockIdx.y * 128;
  if (m0 >= cnt) return;
  int rbase = roff[e];
  int n0 = blockIdx.x * 128;

  __shared__ int tok_s[128];
  __shared__ float sc_s[128];
  __shared__ __align__(16) unsigned short la[128 * 32];
  __shared__ __align__(16) unsigned short lb[128 * 32];

  int tid = threadIdx.x;
  if (tid < 128) {
    int r = m0 + tid;
    tok_s[tid] = (r < cnt) ? tok_list[rbase + r] : -1;
    sc_s[tid] = (r < cnt) ? srow[rbase + r] : 0.f;
  }
  __syncthreads();

  const unsigned short* b = (e < NE) ? (wt2 + (size_t)e * DM * HID) : wst2;

  int wave = tid >> 6, lane = tid & 63;
  int wm = (wave >> 1) << 6, wn = (wave & 1) << 6;
  int lq = lane >> 4, lr = lane & 15;

  int row0 = tid >> 2,         q0 = (tid & 3) << 3;
  int row1 = (256 + tid) >> 2, q1 = q0;

  f32x4 acc[4][4] = {};

  for (int k0 = 0; k0 < HID; k0 += 32) {
    // padding rows read adjacent valid Hg memory; contributions masked at store
    gl2l(Hg + (size_t)(rbase + m0 + row0) * HID + k0 + q0, &la[tid * 8]);
    gl2l(Hg + (size_t)(rbase + m0 + row1) * HID + k0 + q1, &la[(256 + tid) * 8]);
    gl2l(b + (size_t)(n0 + row0) * HID + k0 + q0, &lb[tid * 8]);
    gl2l(b + (size_t)(n0 + row1) * HID + k0 + q1, &lb[(256 + tid) * 8]);
    __syncthreads();
    bf16x8 af[4], bfv[4];
#pragma unroll
    for (int i = 0; i < 4; ++i) {
      af[i]  = *(const bf16x8*)(&la[(wm + i * 16 + lr) * 32 + lq * 8]);
      bfv[i] = *(const bf16x8*)(&lb[(wn + i * 16 + lr) * 32 + lq * 8]);
    }
#pragma unroll
    for (int i = 0; i < 4; ++i)
#pragma unroll
      for (int j = 0; j < 4; ++j)
        acc[i][j] = __builtin_amdgcn_mfma_f32_16x16x32_bf16(af[i], bfv[j], acc[i][j], 0, 0, 0);
    __syncthreads();
  }

#pragma unroll
  for (int i = 0; i < 4; ++i)
#pragma unroll
    for (int j = 0; j < 4; ++j)
#pragma unroll
      for (int r = 0; r < 4; ++r) {
        int lm = wm + i * 16 + lq * 4 + r;
        if (m0 + lm < cnt) {
          int tok = tok_s[lm];
          int ln = wn + j * 16 + lr;
          float v = acc[i][j][r] * sc_s[lm];
          unsafeAtomicAdd(&out[(size_t)tok * DM + n0 + ln], v);
        }
      }
}

// ---------------- launch ----------------
extern "C" void kernel_launch(void* const* d_in, const int* in_sizes, int n_in,
                              void* d_out, int out_size, void* d_ws, size_t ws_size,
                              hipStream_t stream) {
  const float* x   = (const float*)d_in[0];
  const float* wr  = (const float*)d_in[1];
  const float* w1  = (const float*)d_in[2];
  const float* w3  = (const float*)d_in[3];
  const float* w2  = (const float*)d_in[4];
  const float* ws1 = (const float*)d_in[5];
  const float* ws3 = (const float*)d_in[6];
  const float* ws2 = (const float*)d_in[7];
  float* out = (float*)d_out;

  char* p = (char*)d_ws;
  auto alloc = [&](size_t bytes) { char* r = p; p += (bytes + 255) & ~(size_t)255; return r; };
  unsigned short* xb   = (unsigned short*)alloc((size_t)T_TOK * DM * 2);
  unsigned short* wt1  = (unsigned short*)alloc((size_t)NE * HID * DM * 2);
  unsigned short* wt3  = (unsigned short*)alloc((size_t)NE * HID * DM * 2);
  unsigned short* wt2  = (unsigned short*)alloc((size_t)NE * DM * HID * 2);
  unsigned short* wst1 = (unsigned short*)alloc((size_t)HID * DM * 2);
  unsigned short* wst3 = (unsigned short*)alloc((size_t)HID * DM * 2);
  unsigned short* wst2 = (unsigned short*)alloc((size_t)DM * HID * 2);
  unsigned short* Hg   = (unsigned short*)alloc((size_t)RTOT * HID * 2);
  int*   tok_list = (int*)alloc((size_t)RTOT * 4);
  float* srow     = (float*)alloc((size_t)RTOT * 4);
  int*   te       = (int*)alloc((size_t)T_TOK * 2 * 4);
  float* tw       = (float*)alloc((size_t)T_TOK * 2 * 4);
  int*   meta     = (int*)alloc(256);
  (void)ws_size; (void)in_sizes; (void)n_in;

  hipMemsetAsync(meta, 0, 256, stream);
  hipMemsetAsync(out, 0, (size_t)out_size * sizeof(float), stream);

  cast_x_k<<<(T_TOK * DM / 4) / 256, 256, 0, stream>>>(x, xb);

  dim3 tb(32, 8);
  transpose_cast_k<<<dim3(HID / 32, DM / 32, NE), tb, 0, stream>>>(w1, wt1, DM, HID);
  transpose_cast_k<<<dim3(HID / 32, DM / 32, NE), tb, 0, stream>>>(w3, wt3, DM, HID);
  transpose_cast_k<<<dim3(DM / 32, HID / 32, NE), tb, 0, stream>>>(w2, wt2, HID, DM);
  transpose_cast_k<<<dim3(HID / 32, DM / 32, 1), tb, 0, stream>>>(ws1, wst1, DM, HID);
  transpose_cast_k<<<dim3(HID / 32, DM / 32, 1), tb, 0, stream>>>(ws3, wst3, DM, HID);
  transpose_cast_k<<<dim3(DM / 32, HID / 32, 1), tb, 0, stream>>>(ws2, wst2, HID, DM);

  router_k<<<T_TOK / 256, 256, 0, stream>>>(x, wr, meta, te, tw);
  scan_k<<<1, 64, 0, stream>>>(meta);
  build_k<<<T_TOK / 256, 256, 0, stream>>>(te, tw, meta, tok_list, srow);

  gemm1_k<<<dim3(HID / 128, 64, NE + 1), 256, 0, stream>>>(xb, wt1, wt3, wst1, wst3, Hg, tok_list, meta);
  gemm2_k<<<dim3(DM / 128, 64, NE + 1), 256, 0, stream>>>(Hg, wt2, wst2, out, tok_list, srow, meta);
}

// Round 3
// 937.345 us; speedup vs baseline: 1.3452x; 1.3132x over previous
//
#include <hip/hip_runtime.h>
#include <hip/hip_bf16.h>

// Problem constants
#define T_TOK 8192      // BATCH*SEQ
#define DM    1024      // D_MODEL
#define NE    8         // NUM_EXPERTS
#define HID   2048      // HIDDEN == SHARED_HIDDEN
#define NP    4096      // 2*HID: interleaved W1/W3 fused N
#define REXP  16384     // 2*T (expert pair rows)
#define RTOT  24576     // 2*T + T (expert pairs + shared rows)

typedef __attribute__((ext_vector_type(8))) short bf16x8;
typedef __attribute__((ext_vector_type(4))) float f32x4;

__device__ __forceinline__ unsigned short f2bf(float f) {
  unsigned int u = __float_as_uint(f);
  unsigned int r = (u + 0x7FFFu + ((u >> 16) & 1u)) >> 16;
  return (unsigned short)r;
}

// async global -> LDS, 16 bytes per lane; LDS dst = wave-uniform base + lane*16
__device__ __forceinline__ void gl2l(const unsigned short* g, unsigned short* l) {
  __builtin_amdgcn_global_load_lds(
      (const __attribute__((address_space(1))) unsigned int*)g,
      (__attribute__((address_space(3))) unsigned int*)l, 16, 0, 0);
}

// ---------------- cast x (fp32 -> bf16), 4 elems/thread ----------------
__global__ void cast_x_k(const float* __restrict__ x, unsigned short* __restrict__ xb) {
  int i = blockIdx.x * 256 + threadIdx.x;
  float4 v = ((const float4*)x)[i];
  ushort4 o;
  o.x = f2bf(v.x); o.y = f2bf(v.y); o.z = f2bf(v.z); o.w = f2bf(v.w);
  ((ushort4*)xb)[i] = o;
}

// ------------- transpose + cast: src [R,C] fp32 -> dst [C,R] bf16 -------------
__global__ void transpose_cast_k(const float* __restrict__ src, unsigned short* __restrict__ dst,
                                 int R, int C) {
  __shared__ float tile[32][33];
  const float* s = src + (size_t)blockIdx.z * R * C;
  unsigned short* d = dst + (size_t)blockIdx.z * R * C;
  int c0 = blockIdx.x * 32, r0 = blockIdx.y * 32;
  int tx = threadIdx.x, ty = threadIdx.y; // 32 x 8
#pragma unroll
  for (int i = 0; i < 32; i += 8)
    tile[ty + i][tx] = s[(size_t)(r0 + ty + i) * C + c0 + tx];
  __syncthreads();
#pragma unroll
  for (int i = 0; i < 32; i += 8)
    d[(size_t)(c0 + ty + i) * R + r0 + tx] = f2bf(tile[tx][ty + i]);
}

// ---- transpose + cast + interleave: w1,w3 [R=DM, C=HID] -> dst [2C, R] bf16 ----
// dst row f: g=f>>4, r=f&15; g even -> w1 col (g>>1)*16+r; g odd -> w3 col (g>>1)*16+r
__global__ void transpose_ilv_k(const float* __restrict__ s1, const float* __restrict__ s3,
                                unsigned short* __restrict__ dst, int R, int C) {
  __shared__ float t1[32][33], t3[32][33];
  const float* a = s1 + (size_t)blockIdx.z * R * C;
  const float* b = s3 + (size_t)blockIdx.z * R * C;
  unsigned short* d = dst + (size_t)blockIdx.z * 2 * R * C;
  int c0 = blockIdx.x * 32, r0 = blockIdx.y * 32;
  int tx = threadIdx.x, ty = threadIdx.y; // 32 x 8
#pragma unroll
  for (int i = 0; i < 32; i += 8) {
    t1[ty + i][tx] = a[(size_t)(r0 + ty + i) * C + c0 + tx];
    t3[ty + i][tx] = b[(size_t)(r0 + ty + i) * C + c0 + tx];
  }
  __syncthreads();
#pragma unroll
  for (int i = 0; i < 32; i += 8) {
    int c = c0 + ty + i;
    int f1 = ((c & ~15) << 1) | (c & 15);
    d[(size_t)f1 * R + r0 + tx] = f2bf(t1[tx][ty + i]);
    d[(size_t)(f1 + 16) * R + r0 + tx] = f2bf(t3[tx][ty + i]);
  }
}

// ---------------- router: fp32 logits -> softmax -> top2 ----------------
// meta layout (ints): [0..7]=counts  [8..23]=roff  [24..31]=cursor  [32..47]=rcount
__global__ void router_k(const float* __restrict__ x, const float* __restrict__ wr,
                         int* __restrict__ meta, int* __restrict__ te, float* __restrict__ tw) {
  int t = blockIdx.x * 256 + threadIdx.x;
  const float* xr = x + (size_t)t * DM;
  float acc[NE] = {};
  for (int d = 0; d < DM; d += 4) {
    float4 v = *(const float4*)(xr + d);
#pragma unroll
    for (int e = 0; e < NE; ++e) {
      acc[e] += v.x * wr[(d + 0) * NE + e] + v.y * wr[(d + 1) * NE + e]
              + v.z * wr[(d + 2) * NE + e] + v.w * wr[(d + 3) * NE + e];
    }
  }
  float m = acc[0];
#pragma unroll
  for (int e = 1; e < NE; ++e) m = fmaxf(m, acc[e]);
  float p[NE]; float s = 0.f;
#pragma unroll
  for (int e = 0; e < NE; ++e) { p[e] = __expf(acc[e] - m); s += p[e]; }
  float inv = 1.f / s;
  int i0 = 0;
#pragma unroll
  for (int e = 1; e < NE; ++e) if (p[e] > p[i0]) i0 = e;
  int i1 = (i0 == 0) ? 1 : 0;
#pragma unroll
  for (int e = 0; e < NE; ++e) if (e != i0 && p[e] > p[i1]) i1 = e;
  atomicAdd(&meta[i0], 1);
  atomicAdd(&meta[i1], 1);
  te[t * 2 + 0] = i0; te[t * 2 + 1] = i1;
  tw[t * 2 + 0] = p[i0] * inv; tw[t * 2 + 1] = p[i1] * inv;
}

// ---------------- tiny scan: counts -> row offsets ----------------
__global__ void scan_k(int* __restrict__ meta) {
  if (threadIdx.x == 0) {
    int* counts = meta; int* roff = meta + 8; int* cursor = meta + 24; int* rcount = meta + 32;
    int acc = 0;
    for (int e = 0; e < NE; ++e) { roff[e] = acc; cursor[e] = acc; rcount[e] = counts[e]; acc += counts[e]; }
    roff[NE] = REXP;      // shared "expert" rows live at [REXP, RTOT)
    rcount[NE] = T_TOK;
  }
}

// ---------------- build compacted pair lists ----------------
__global__ void build_k(const int* __restrict__ te, const float* __restrict__ tw,
                        int* __restrict__ meta, int* __restrict__ tok_list, float* __restrict__ srow) {
  int t = blockIdx.x * 256 + threadIdx.x;
  int* cursor = meta + 24;
#pragma unroll
  for (int k = 0; k < 2; ++k) {
    int e = te[t * 2 + k];
    int pos = atomicAdd(&cursor[e], 1);
    tok_list[pos] = t;
    srow[pos] = tw[t * 2 + k] * (2.0f / 3.0f);   // moe_out * K/(K+1)
  }
  tok_list[REXP + t] = t;
  srow[REXP + t] = 1.0f / 3.0f;                  // shared / (K+1)
}

// ------- GEMM1: fused dual-GEMM over interleaved W13, N' = 4096 -------
// A: xb gathered rows; B: wt13 [n'=NP][k=DM]; out Hg [RTOT][HID] bf16 after SwiGLU
__global__ __launch_bounds__(256) void gemm1_k(
    const unsigned short* __restrict__ xb,
    const unsigned short* __restrict__ wt13, const unsigned short* __restrict__ wst13,
    unsigned short* __restrict__ Hg,
    const int* __restrict__ tok_list, const int* __restrict__ meta) {
  const int* roff = meta + 8; const int* rcount = meta + 32;
  int e = blockIdx.z;
  int cnt = rcount[e];
  int m0 = blockIdx.y * 128;
  if (m0 >= cnt) return;
  int rbase = roff[e];
  int n0 = blockIdx.x * 128;   // over N' = 2*HID

  __shared__ int tok_s[128];
  __shared__ __align__(16) unsigned short la[128 * 32];
  __shared__ __align__(16) unsigned short lb[128 * 32];

  int tid = threadIdx.x;
  if (tid < 128) {
    int r = m0 + tid;
    tok_s[tid] = (r < cnt) ? tok_list[rbase + r] : 0;  // pad rows -> token 0, masked at store
  }
  __syncthreads();

  const unsigned short* bsrc = (e < NE) ? (wt13 + (size_t)e * NP * DM) : wst13;

  int row0 = tid >> 2, q0 = (tid & 3) << 3;
  int row1 = row0 + 64;
  const unsigned short* ap0 = xb + (size_t)tok_s[row0] * DM + q0;
  const unsigned short* ap1 = xb + (size_t)tok_s[row1] * DM + q0;
  const unsigned short* bp0 = bsrc + (size_t)(n0 + row0) * DM + q0;
  const unsigned short* bp1 = bsrc + (size_t)(n0 + row1) * DM + q0;

  int wave = tid >> 6, lane = tid & 63;
  int wm = (wave >> 1) << 6, wn = (wave & 1) << 6;
  int lq = lane >> 4, lr = lane & 15;

  f32x4 acc[4][4] = {};

  for (int k0 = 0; k0 < DM; k0 += 32) {
    gl2l(ap0, &la[tid * 8]);
    gl2l(ap1, &la[(256 + tid) * 8]);
    gl2l(bp0, &lb[tid * 8]);
    gl2l(bp1, &lb[(256 + tid) * 8]);
    ap0 += 32; ap1 += 32; bp0 += 32; bp1 += 32;
    __syncthreads();
    bf16x8 af[4], bfv[4];
#pragma unroll
    for (int i = 0; i < 4; ++i) {
      af[i]  = *(const bf16x8*)(&la[(wm + i * 16 + lr) * 32 + lq * 8]);
      bfv[i] = *(const bf16x8*)(&lb[(wn + i * 16 + lr) * 32 + lq * 8]);
    }
#pragma unroll
    for (int i = 0; i < 4; ++i)
#pragma unroll
      for (int j = 0; j < 4; ++j)
        acc[i][j] = __builtin_amdgcn_mfma_f32_16x16x32_bf16(af[i], bfv[j], acc[i][j], 0, 0, 0);
    __syncthreads();
  }

  // epilogue: j even = W1 (gate), j odd = W3 (up), same hid cols within wave
  int hbase = (n0 + wn) >> 1;
#pragma unroll
  for (int i = 0; i < 4; ++i)
#pragma unroll
    for (int jp = 0; jp < 2; ++jp)
#pragma unroll
      for (int r = 0; r < 4; ++r) {
        int lm = wm + i * 16 + lq * 4 + r;          // C/D: row = quad*4 + reg
        if (m0 + lm < cnt) {
          float a = acc[i][2 * jp][r];
          float c = acc[i][2 * jp + 1][r];
          float h = (a / (1.f + __expf(-a))) * c;   // silu(a) * c
          Hg[(size_t)(rbase + m0 + lm) * HID + hbase + jp * 16 + lr] = f2bf(h);
        }
      }
}

// ---------------- GEMM2: out[tok] += scale * (Hg_row @ W2) ----------------
__global__ __launch_bounds__(256) void gemm2_k(
    const unsigned short* __restrict__ Hg,
    const unsigned short* __restrict__ wt2, const unsigned short* __restrict__ wst2,
    float* __restrict__ out,
    const int* __restrict__ tok_list, const float* __restrict__ srow,
    const int* __restrict__ meta) {
  const int* roff = meta + 8; const int* rcount = meta + 32;
  int e = blockIdx.z;
  int cnt = rcount[e];
  int m0 = blockIdx.y * 128;
  if (m0 >= cnt) return;
  int rbase = roff[e];
  int n0 = blockIdx.x * 128;

  __shared__ int tok_s[128];
  __shared__ float sc_s[128];
  __shared__ __align__(16) unsigned short la[128 * 32];
  __shared__ __align__(16) unsigned short lb[128 * 32];

  int tid = threadIdx.x;
  if (tid < 128) {
    int r = m0 + tid;
    tok_s[tid] = (r < cnt) ? tok_list[rbase + r] : -1;
    sc_s[tid] = (r < cnt) ? srow[rbase + r] : 0.f;
  }
  __syncthreads();

  const unsigned short* b = (e < NE) ? (wt2 + (size_t)e * DM * HID) : wst2;

  int wave = tid >> 6, lane = tid & 63;
  int wm = (wave >> 1) << 6, wn = (wave & 1) << 6;
  int lq = lane >> 4, lr = lane & 15;

  int row0 = tid >> 2, q0 = (tid & 3) << 3;
  int row1 = row0 + 64;
  // pad rows beyond cnt read adjacent valid Hg memory; contributions masked at store
  const unsigned short* ap0 = Hg + (size_t)(rbase + m0 + row0) * HID + q0;
  const unsigned short* ap1 = Hg + (size_t)(rbase + m0 + row1) * HID + q0;
  const unsigned short* bp0 = b + (size_t)(n0 + row0) * HID + q0;
  const unsigned short* bp1 = b + (size_t)(n0 + row1) * HID + q0;

  f32x4 acc[4][4] = {};

  for (int k0 = 0; k0 < HID; k0 += 32) {
    gl2l(ap0, &la[tid * 8]);
    gl2l(ap1, &la[(256 + tid) * 8]);
    gl2l(bp0, &lb[tid * 8]);
    gl2l(bp1, &lb[(256 + tid) * 8]);
    ap0 += 32; ap1 += 32; bp0 += 32; bp1 += 32;
    __syncthreads();
    bf16x8 af[4], bfv[4];
#pragma unroll
    for (int i = 0; i < 4; ++i) {
      af[i]  = *(const bf16x8*)(&la[(wm + i * 16 + lr) * 32 + lq * 8]);
      bfv[i] = *(const bf16x8*)(&lb[(wn + i * 16 + lr) * 32 + lq * 8]);
    }
#pragma unroll
    for (int i = 0; i < 4; ++i)
#pragma unroll
      for (int j = 0; j < 4; ++j)
        acc[i][j] = __builtin_amdgcn_mfma_f32_16x16x32_bf16(af[i], bfv[j], acc[i][j], 0, 0, 0);
    __syncthreads();
  }

#pragma unroll
  for (int i = 0; i < 4; ++i)
#pragma unroll
    for (int j = 0; j < 4; ++j)
#pragma unroll
      for (int r = 0; r < 4; ++r) {
        int lm = wm + i * 16 + lq * 4 + r;
        if (m0 + lm < cnt) {
          int tok = tok_s[lm];
          int ln = wn + j * 16 + lr;
          float v = acc[i][j][r] * sc_s[lm];
          unsafeAtomicAdd(&out[(size_t)tok * DM + n0 + ln], v);
        }
      }
}

// ---------------- launch ----------------
extern "C" void kernel_launch(void* const* d_in, const int* in_sizes, int n_in,
                              void* d_out, int out_size, void* d_ws, size_t ws_size,
                              hipStream_t stream) {
  const float* x   = (const float*)d_in[0];
  const float* wr  = (const float*)d_in[1];
  const float* w1  = (const float*)d_in[2];
  const float* w3  = (const float*)d_in[3];
  const float* w2  = (const float*)d_in[4];
  const float* ws1 = (const float*)d_in[5];
  const float* ws3 = (const float*)d_in[6];
  const float* ws2 = (const float*)d_in[7];
  float* out = (float*)d_out;

  char* p = (char*)d_ws;
  auto alloc = [&](size_t bytes) { char* r = p; p += (bytes + 255) & ~(size_t)255; return r; };
  unsigned short* xb    = (unsigned short*)alloc((size_t)T_TOK * DM * 2);
  unsigned short* wt13  = (unsigned short*)alloc((size_t)NE * NP * DM * 2);
  unsigned short* wst13 = (unsigned short*)alloc((size_t)NP * DM * 2);
  unsigned short* wt2   = (unsigned short*)alloc((size_t)NE * DM * HID * 2);
  unsigned short* wst2  = (unsigned short*)alloc((size_t)DM * HID * 2);
  unsigned short* Hg    = (unsigned short*)alloc((size_t)RTOT * HID * 2);
  int*   tok_list = (int*)alloc((size_t)RTOT * 4);
  float* srow     = (float*)alloc((size_t)RTOT * 4);
  int*   te       = (int*)alloc((size_t)T_TOK * 2 * 4);
  float* tw       = (float*)alloc((size_t)T_TOK * 2 * 4);
  int*   meta     = (int*)alloc(256);
  (void)ws_size; (void)in_sizes; (void)n_in;

  hipMemsetAsync(meta, 0, 256, stream);
  hipMemsetAsync(out, 0, (size_t)out_size * sizeof(float), stream);

  cast_x_k<<<(T_TOK * DM / 4) / 256, 256, 0, stream>>>(x, xb);

  dim3 tb(32, 8);
  transpose_ilv_k<<<dim3(HID / 32, DM / 32, NE), tb, 0, stream>>>(w1, w3, wt13, DM, HID);
  transpose_ilv_k<<<dim3(HID / 32, DM / 32, 1), tb, 0, stream>>>(ws1, ws3, wst13, DM, HID);
  transpose_cast_k<<<dim3(DM / 32, HID / 32, NE), tb, 0, stream>>>(w2, wt2, HID, DM);
  transpose_cast_k<<<dim3(DM / 32, HID / 32, 1), tb, 0, stream>>>(ws2, wst2, HID, DM);

  router_k<<<T_TOK / 256, 256, 0, stream>>>(x, wr, meta, te, tw);
  scan_k<<<1, 64, 0, stream>>>(meta);
  build_k<<<T_TOK / 256, 256, 0, stream>>>(te, tw, meta, tok_list, srow);

  gemm1_k<<<dim3(NP / 128, 64, NE + 1), 256, 0, stream>>>(xb, wt13, wst13, Hg, tok_list, meta);
  gemm2_k<<<dim3(DM / 128, 64, NE + 1), 256, 0, stream>>>(Hg, wt2, wst2, out, tok_list, srow, meta);
}

// Round 4
// 892.945 us; speedup vs baseline: 1.4121x; 1.0497x over previous
//
#include <hip/hip_runtime.h>
#include <hip/hip_bf16.h>

// Problem constants
#define T_TOK 8192      // BATCH*SEQ
#define DM    1024      // D_MODEL
#define NE    8         // NUM_EXPERTS
#define HID   2048      // HIDDEN == SHARED_HIDDEN
#define NP    4096      // 2*HID: interleaved W1/W3 fused N
#define REXP  16384     // 2*T (expert pair rows)
#define RTOT  24576     // 2*T + T (expert pairs + shared rows)

typedef __attribute__((ext_vector_type(8))) short bf16x8;
typedef __attribute__((ext_vector_type(4))) float f32x4;

__device__ __forceinline__ unsigned short f2bf(float f) {
  unsigned int u = __float_as_uint(f);
  unsigned int r = (u + 0x7FFFu + ((u >> 16) & 1u)) >> 16;
  return (unsigned short)r;
}
__device__ __forceinline__ float b2f(unsigned short h) {
  return __uint_as_float((unsigned int)h << 16);
}

// async global -> LDS, 16 bytes per lane; LDS dst = wave-uniform base + lane*16
__device__ __forceinline__ void gl2l(const unsigned short* g, unsigned short* l) {
  __builtin_amdgcn_global_load_lds(
      (const __attribute__((address_space(1))) unsigned int*)g,
      (__attribute__((address_space(3))) unsigned int*)l, 16, 0, 0);
}

// ---------------- cast x (fp32 -> bf16), 4 elems/thread ----------------
__global__ void cast_x_k(const float* __restrict__ x, unsigned short* __restrict__ xb) {
  int i = blockIdx.x * 256 + threadIdx.x;
  float4 v = ((const float4*)x)[i];
  ushort4 o;
  o.x = f2bf(v.x); o.y = f2bf(v.y); o.z = f2bf(v.z); o.w = f2bf(v.w);
  ((ushort4*)xb)[i] = o;
}

// ---- transpose + cast + interleave w1/w3: [DM, HID] fp32 -> wt13 [NP, DM] bf16 ----
// out row f for col c: f = ((c&~15)<<1)|(c&15), w3 at f+16. z = expert (8 = shared).
__global__ __launch_bounds__(256) void tilv_k(const float* __restrict__ w1, const float* __restrict__ w3,
                                              const float* __restrict__ s1, const float* __restrict__ s3,
                                              unsigned short* __restrict__ wt13,
                                              unsigned short* __restrict__ wst13) {
  int e = blockIdx.z;
  const float* a = (e < NE) ? w1 + (size_t)e * DM * HID : s1;
  const float* b = (e < NE) ? w3 + (size_t)e * DM * HID : s3;
  unsigned short* d = (e < NE) ? wt13 + (size_t)e * NP * DM : wst13;
  int c0 = blockIdx.x * 64, r0 = blockIdx.y * 64;
  __shared__ float t1[64][65], t3[64][65];
  int tid = threadIdx.x;
  int rr = tid >> 4;            // 0..15
  int cc = (tid & 15) << 2;     // 0..60 step 4
#pragma unroll
  for (int i = 0; i < 64; i += 16) {
    float4 v1 = *(const float4*)(a + (size_t)(r0 + rr + i) * HID + c0 + cc);
    float4 v3 = *(const float4*)(b + (size_t)(r0 + rr + i) * HID + c0 + cc);
    t1[rr + i][cc] = v1.x; t1[rr + i][cc + 1] = v1.y; t1[rr + i][cc + 2] = v1.z; t1[rr + i][cc + 3] = v1.w;
    t3[rr + i][cc] = v3.x; t3[rr + i][cc + 1] = v3.y; t3[rr + i][cc + 2] = v3.z; t3[rr + i][cc + 3] = v3.w;
  }
  __syncthreads();
  int ft0 = tid >> 4;
  int rt = (tid & 15) << 2;
#pragma unroll
  for (int i = 0; i < 4; ++i) {
    int ft = ft0 + 16 * i;
    int c = c0 + ft;
    int f = ((c & ~15) << 1) | (c & 15);
    ushort4 o1, o3;
    o1.x = f2bf(t1[rt + 0][ft]); o1.y = f2bf(t1[rt + 1][ft]);
    o1.z = f2bf(t1[rt + 2][ft]); o1.w = f2bf(t1[rt + 3][ft]);
    o3.x = f2bf(t3[rt + 0][ft]); o3.y = f2bf(t3[rt + 1][ft]);
    o3.z = f2bf(t3[rt + 2][ft]); o3.w = f2bf(t3[rt + 3][ft]);
    *(ushort4*)(d + (size_t)f * DM + r0 + rt) = o1;
    *(ushort4*)(d + (size_t)(f + 16) * DM + r0 + rt) = o3;
  }
}

// ---- transpose + cast w2: [HID, DM] fp32 -> [DM, HID] bf16. z = expert (8 = shared). ----
__global__ __launch_bounds__(256) void w2t_k(const float* __restrict__ w2, const float* __restrict__ s2,
                                             unsigned short* __restrict__ wt2,
                                             unsigned short* __restrict__ wst2) {
  int e = blockIdx.z;
  const float* a = (e < NE) ? w2 + (size_t)e * HID * DM : s2;
  unsigned short* d = (e < NE) ? wt2 + (size_t)e * DM * HID : wst2;
  int c0 = blockIdx.x * 64, r0 = blockIdx.y * 64;
  __shared__ float t1[64][65];
  int tid = threadIdx.x;
  int rr = tid >> 4;
  int cc = (tid & 15) << 2;
#pragma unroll
  for (int i = 0; i < 64; i += 16) {
    float4 v1 = *(const float4*)(a + (size_t)(r0 + rr + i) * DM + c0 + cc);
    t1[rr + i][cc] = v1.x; t1[rr + i][cc + 1] = v1.y; t1[rr + i][cc + 2] = v1.z; t1[rr + i][cc + 3] = v1.w;
  }
  __syncthreads();
  int ft0 = tid >> 4;
  int rt = (tid & 15) << 2;
#pragma unroll
  for (int i = 0; i < 4; ++i) {
    int ft = ft0 + 16 * i;
    ushort4 o;
    o.x = f2bf(t1[rt + 0][ft]); o.y = f2bf(t1[rt + 1][ft]);
    o.z = f2bf(t1[rt + 2][ft]); o.w = f2bf(t1[rt + 3][ft]);
    *(ushort4*)(d + (size_t)(c0 + ft) * HID + r0 + rt) = o;
  }
}

// ---------------- router: fp32 logits -> softmax -> top2 ----------------
// meta layout (ints): [0..7]=counts  [8..23]=roff  [24..31]=cursor  [32..47]=rcount
__global__ void router_k(const float* __restrict__ x, const float* __restrict__ wr,
                         int* __restrict__ meta, int* __restrict__ te, float* __restrict__ tw) {
  int t = blockIdx.x * 256 + threadIdx.x;
  const float* xr = x + (size_t)t * DM;
  float acc[NE] = {};
  for (int d = 0; d < DM; d += 4) {
    float4 v = *(const float4*)(xr + d);
#pragma unroll
    for (int e = 0; e < NE; ++e) {
      acc[e] += v.x * wr[(d + 0) * NE + e] + v.y * wr[(d + 1) * NE + e]
              + v.z * wr[(d + 2) * NE + e] + v.w * wr[(d + 3) * NE + e];
    }
  }
  float m = acc[0];
#pragma unroll
  for (int e = 1; e < NE; ++e) m = fmaxf(m, acc[e]);
  float p[NE]; float s = 0.f;
#pragma unroll
  for (int e = 0; e < NE; ++e) { p[e] = __expf(acc[e] - m); s += p[e]; }
  float inv = 1.f / s;
  int i0 = 0;
#pragma unroll
  for (int e = 1; e < NE; ++e) if (p[e] > p[i0]) i0 = e;
  int i1 = (i0 == 0) ? 1 : 0;
#pragma unroll
  for (int e = 0; e < NE; ++e) if (e != i0 && p[e] > p[i1]) i1 = e;
  atomicAdd(&meta[i0], 1);
  atomicAdd(&meta[i1], 1);
  te[t * 2 + 0] = i0; te[t * 2 + 1] = i1;
  tw[t * 2 + 0] = p[i0] * inv; tw[t * 2 + 1] = p[i1] * inv;
}

// ---------------- tiny scan: counts -> row offsets ----------------
__global__ void scan_k(int* __restrict__ meta) {
  if (threadIdx.x == 0) {
    int* counts = meta; int* roff = meta + 8; int* cursor = meta + 24; int* rcount = meta + 32;
    int acc = 0;
    for (int e = 0; e < NE; ++e) { roff[e] = acc; cursor[e] = acc; rcount[e] = counts[e]; acc += counts[e]; }
    roff[NE] = REXP;      // shared "expert" rows live at [REXP, RTOT)
    rcount[NE] = T_TOK;
  }
}

// ---------------- build compacted pair lists + inverse map ----------------
__global__ void build_k(const int* __restrict__ te, const float* __restrict__ tw,
                        int* __restrict__ meta, int* __restrict__ tok_list,
                        float* __restrict__ srow, int* __restrict__ pos) {
  int t = blockIdx.x * 256 + threadIdx.x;
  int* cursor = meta + 24;
#pragma unroll
  for (int k = 0; k < 2; ++k) {
    int e = te[t * 2 + k];
    int q = atomicAdd(&cursor[e], 1);
    tok_list[q] = t;
    srow[q] = tw[t * 2 + k] * (2.0f / 3.0f);   // moe_out * K/(K+1)
    pos[t * 2 + k] = q;
  }
  tok_list[REXP + t] = t;
  srow[REXP + t] = 1.0f / 3.0f;                // shared / (K+1)
}

// ------- GEMM1: fused dual-GEMM over interleaved W13, N' = 4096 -------
__global__ __launch_bounds__(256) void gemm1_k(
    const unsigned short* __restrict__ xb,
    const unsigned short* __restrict__ wt13, const unsigned short* __restrict__ wst13,
    unsigned short* __restrict__ Hg,
    const int* __restrict__ tok_list, const int* __restrict__ meta) {
  const int* roff = meta + 8; const int* rcount = meta + 32;
  int e = blockIdx.z;
  int cnt = rcount[e];
  int m0 = blockIdx.y * 128;
  if (m0 >= cnt) return;
  int rbase = roff[e];
  int n0 = blockIdx.x * 128;   // over N' = 2*HID

  __shared__ int tok_s[128];
  __shared__ __align__(16) unsigned short la[128 * 32];
  __shared__ __align__(16) unsigned short lb[128 * 32];

  int tid = threadIdx.x;
  if (tid < 128) {
    int r = m0 + tid;
    tok_s[tid] = (r < cnt) ? tok_list[rbase + r] : 0;  // pad rows -> token 0, masked at store
  }
  __syncthreads();

  const unsigned short* bsrc = (e < NE) ? (wt13 + (size_t)e * NP * DM) : wst13;

  int row0 = tid >> 2, q0 = (tid & 3) << 3;
  int row1 = row0 + 64;
  const unsigned short* ap0 = xb + (size_t)tok_s[row0] * DM + q0;
  const unsigned short* ap1 = xb + (size_t)tok_s[row1] * DM + q0;
  const unsigned short* bp0 = bsrc + (size_t)(n0 + row0) * DM + q0;
  const unsigned short* bp1 = bsrc + (size_t)(n0 + row1) * DM + q0;

  int wave = tid >> 6, lane = tid & 63;
  int wm = (wave >> 1) << 6, wn = (wave & 1) << 6;
  int lq = lane >> 4, lr = lane & 15;

  f32x4 acc[4][4] = {};

  for (int k0 = 0; k0 < DM; k0 += 32) {
    gl2l(ap0, &la[tid * 8]);
    gl2l(ap1, &la[(256 + tid) * 8]);
    gl2l(bp0, &lb[tid * 8]);
    gl2l(bp1, &lb[(256 + tid) * 8]);
    ap0 += 32; ap1 += 32; bp0 += 32; bp1 += 32;
    __syncthreads();
    bf16x8 af[4], bfv[4];
#pragma unroll
    for (int i = 0; i < 4; ++i) {
      af[i]  = *(const bf16x8*)(&la[(wm + i * 16 + lr) * 32 + lq * 8]);
      bfv[i] = *(const bf16x8*)(&lb[(wn + i * 16 + lr) * 32 + lq * 8]);
    }
#pragma unroll
    for (int i = 0; i < 4; ++i)
#pragma unroll
      for (int j = 0; j < 4; ++j)
        acc[i][j] = __builtin_amdgcn_mfma_f32_16x16x32_bf16(af[i], bfv[j], acc[i][j], 0, 0, 0);
    __syncthreads();
  }

  // epilogue: j even = W1 (gate), j odd = W3 (up), same hid cols within wave
  int hbase = (n0 + wn) >> 1;
#pragma unroll
  for (int i = 0; i < 4; ++i)
#pragma unroll
    for (int jp = 0; jp < 2; ++jp)
#pragma unroll
      for (int r = 0; r < 4; ++r) {
        int lm = wm + i * 16 + lq * 4 + r;          // C/D: row = quad*4 + reg
        if (m0 + lm < cnt) {
          float a = acc[i][2 * jp][r];
          float c = acc[i][2 * jp + 1][r];
          float h = (a / (1.f + __expf(-a))) * c;   // silu(a) * c
          Hg[(size_t)(rbase + m0 + lm) * HID + hbase + jp * 16 + lr] = f2bf(h);
        }
      }
}

// ------- GEMM2: yr[row] = scale * (Hg_row @ W2), dense bf16 store (no atomics) -------
__global__ __launch_bounds__(256) void gemm2_k(
    const unsigned short* __restrict__ Hg,
    const unsigned short* __restrict__ wt2, const unsigned short* __restrict__ wst2,
    unsigned short* __restrict__ yr,
    const float* __restrict__ srow, const int* __restrict__ meta) {
  const int* roff = meta + 8; const int* rcount = meta + 32;
  int e = blockIdx.z;
  int cnt = rcount[e];
  int m0 = blockIdx.y * 128;
  if (m0 >= cnt) return;
  int rbase = roff[e];
  int n0 = blockIdx.x * 128;

  __shared__ float sc_s[128];
  __shared__ __align__(16) unsigned short la[128 * 32];
  __shared__ __align__(16) unsigned short lb[128 * 32];

  int tid = threadIdx.x;
  if (tid < 128) {
    int r = m0 + tid;
    sc_s[tid] = (r < cnt) ? srow[rbase + r] : 0.f;
  }
  __syncthreads();

  const unsigned short* b = (e < NE) ? (wt2 + (size_t)e * DM * HID) : wst2;

  int wave = tid >> 6, lane = tid & 63;
  int wm = (wave >> 1) << 6, wn = (wave & 1) << 6;
  int lq = lane >> 4, lr = lane & 15;

  int row0 = tid >> 2, q0 = (tid & 3) << 3;
  int row1 = row0 + 64;
  // pad rows beyond cnt read adjacent valid Hg memory; contributions masked at store
  const unsigned short* ap0 = Hg + (size_t)(rbase + m0 + row0) * HID + q0;
  const unsigned short* ap1 = Hg + (size_t)(rbase + m0 + row1) * HID + q0;
  const unsigned short* bp0 = b + (size_t)(n0 + row0) * HID + q0;
  const unsigned short* bp1 = b + (size_t)(n0 + row1) * HID + q0;

  f32x4 acc[4][4] = {};

  for (int k0 = 0; k0 < HID; k0 += 32) {
    gl2l(ap0, &la[tid * 8]);
    gl2l(ap1, &la[(256 + tid) * 8]);
    gl2l(bp0, &lb[tid * 8]);
    gl2l(bp1, &lb[(256 + tid) * 8]);
    ap0 += 32; ap1 += 32; bp0 += 32; bp1 += 32;
    __syncthreads();
    bf16x8 af[4], bfv[4];
#pragma unroll
    for (int i = 0; i < 4; ++i) {
      af[i]  = *(const bf16x8*)(&la[(wm + i * 16 + lr) * 32 + lq * 8]);
      bfv[i] = *(const bf16x8*)(&lb[(wn + i * 16 + lr) * 32 + lq * 8]);
    }
#pragma unroll
    for (int i = 0; i < 4; ++i)
#pragma unroll
      for (int j = 0; j < 4; ++j)
        acc[i][j] = __builtin_amdgcn_mfma_f32_16x16x32_bf16(af[i], bfv[j], acc[i][j], 0, 0, 0);
    __syncthreads();
  }

#pragma unroll
  for (int i = 0; i < 4; ++i)
#pragma unroll
    for (int j = 0; j < 4; ++j)
#pragma unroll
      for (int r = 0; r < 4; ++r) {
        int lm = wm + i * 16 + lq * 4 + r;
        if (m0 + lm < cnt) {
          int ln = wn + j * 16 + lr;
          yr[(size_t)(rbase + m0 + lm) * DM + n0 + ln] = f2bf(acc[i][j][r] * sc_s[lm]);
        }
      }
}

// ------- combine: out[t] = yr[p0] + yr[p1] + yr[REXP+t]  (fp32 out) -------
__global__ __launch_bounds__(256) void combine_k(const unsigned short* __restrict__ yr,
                                                 const int* __restrict__ pos,
                                                 float* __restrict__ out) {
  int t = blockIdx.x;
  int p0 = pos[2 * t], p1 = pos[2 * t + 1];
  int d = threadIdx.x << 2;
  ushort4 a = *(const ushort4*)(yr + (size_t)p0 * DM + d);
  ushort4 b = *(const ushort4*)(yr + (size_t)p1 * DM + d);
  ushort4 c = *(const ushort4*)(yr + (size_t)(REXP + t) * DM + d);
  float4 o;
  o.x = b2f(a.x) + b2f(b.x) + b2f(c.x);
  o.y = b2f(a.y) + b2f(b.y) + b2f(c.y);
  o.z = b2f(a.z) + b2f(b.z) + b2f(c.z);
  o.w = b2f(a.w) + b2f(b.w) + b2f(c.w);
  *(float4*)(out + (size_t)t * DM + d) = o;
}

// ---------------- launch ----------------
extern "C" void kernel_launch(void* const* d_in, const int* in_sizes, int n_in,
                              void* d_out, int out_size, void* d_ws, size_t ws_size,
                              hipStream_t stream) {
  const float* x   = (const float*)d_in[0];
  const float* wr  = (const float*)d_in[1];
  const float* w1  = (const float*)d_in[2];
  const float* w3  = (const float*)d_in[3];
  const float* w2  = (const float*)d_in[4];
  const float* ws1 = (const float*)d_in[5];
  const float* ws3 = (const float*)d_in[6];
  const float* ws2 = (const float*)d_in[7];
  float* out = (float*)d_out;

  char* p = (char*)d_ws;
  auto alloc = [&](size_t bytes) { char* r = p; p += (bytes + 255) & ~(size_t)255; return r; };
  unsigned short* xb    = (unsigned short*)alloc((size_t)T_TOK * DM * 2);
  unsigned short* wt13  = (unsigned short*)alloc((size_t)NE * NP * DM * 2);
  unsigned short* wst13 = (unsigned short*)alloc((size_t)NP * DM * 2);
  unsigned short* wt2   = (unsigned short*)alloc((size_t)NE * DM * HID * 2);
  unsigned short* wst2  = (unsigned short*)alloc((size_t)DM * HID * 2);
  unsigned short* Hg    = (unsigned short*)alloc((size_t)RTOT * HID * 2);
  int*   tok_list = (int*)alloc((size_t)RTOT * 4);
  float* srow     = (float*)alloc((size_t)RTOT * 4);
  int*   te       = (int*)alloc((size_t)T_TOK * 2 * 4);
  float* tw       = (float*)alloc((size_t)T_TOK * 2 * 4);
  int*   pos      = (int*)alloc((size_t)T_TOK * 2 * 4);
  int*   meta     = (int*)alloc(256);
  // yr aliases wt13: wt13 (64 MB) is dead after gemm1; yr (48 MB) is written by
  // gemm2 which runs strictly after gemm1 on the same stream.
  unsigned short* yr = wt13;
  (void)ws_size; (void)in_sizes; (void)n_in;

  hipMemsetAsync(meta, 0, 256, stream);

  cast_x_k<<<(T_TOK * DM / 4) / 256, 256, 0, stream>>>(x, xb);

  tilv_k<<<dim3(HID / 64, DM / 64, NE + 1), 256, 0, stream>>>(w1, w3, ws1, ws3, wt13, wst13);
  w2t_k<<<dim3(DM / 64, HID / 64, NE + 1), 256, 0, stream>>>(w2, ws2, wt2, wst2);

  router_k<<<T_TOK / 256, 256, 0, stream>>>(x, wr, meta, te, tw);
  scan_k<<<1, 64, 0, stream>>>(meta);
  build_k<<<T_TOK / 256, 256, 0, stream>>>(te, tw, meta, tok_list, srow, pos);

  gemm1_k<<<dim3(NP / 128, 64, NE + 1), 256, 0, stream>>>(xb, wt13, wst13, Hg, tok_list, meta);
  gemm2_k<<<dim3(DM / 128, 64, NE + 1), 256, 0, stream>>>(Hg, wt2, wst2, yr, srow, meta);
  combine_k<<<T_TOK, 256, 0, stream>>>(yr, pos, out);
}